// Round 4
// baseline (1415.522 us; speedup 1.0000x reference)
//
#include <hip/hip_runtime.h>
#include <hip/hip_bf16.h>
#include <cstdint>

#define N_NODES 100000
#define NPB 128                       // nodes per bucket (power of two)
#define NB ((N_NODES + NPB - 1) / NPB) // 782 buckets

// ---------------- degree / dinv ----------------

__global__ void k_degree(const int* __restrict__ dst, int* __restrict__ cnt, int E) {
    int e = blockIdx.x * blockDim.x + threadIdx.x;
    if (e < E) atomicAdd(&cnt[dst[e]], 1);
}

__global__ void k_dinv(const int* __restrict__ cnt, float* __restrict__ dinv, int n) {
    int i = blockIdx.x * blockDim.x + threadIdx.x;
    if (i < n) dinv[i] = rsqrtf((float)cnt[i] + 1.0f);
}

// single-block exclusive scan over cnt[0..n) -> row_start[0..n]
__global__ void k_scan(const int* __restrict__ cnt, int* __restrict__ row_start, int n) {
    __shared__ int s[1024];
    int t = threadIdx.x;
    int chunk = (n + 1023) / 1024;
    int lo = t * chunk, hi = min(lo + chunk, n);
    int sum = 0;
    for (int i = lo; i < hi; ++i) sum += cnt[i];
    s[t] = sum;
    __syncthreads();
    for (int off = 1; off < 1024; off <<= 1) {
        int v = (t >= off) ? s[t - off] : 0;
        __syncthreads();
        s[t] += v;
        __syncthreads();
    }
    int base = (t == 0) ? 0 : s[t - 1];
    for (int i = lo; i < hi; ++i) { row_start[i] = base; base += cnt[i]; }
    if (t == 1023) row_start[n] = base;
}

__global__ void k_initcur(const int* __restrict__ row_start, int* __restrict__ cursor) {
    int b = blockIdx.x * blockDim.x + threadIdx.x;
    if (b < NB) cursor[b] = row_start[b << 7];
}

// ---------------- write-friendly bucket sort of edges ----------------
// Each block: LDS histogram of its chunk over NB buckets, reserve one contiguous
// run per bucket (1 global atomic), then scatter into block-private runs.
// Payload: packed (src<<7)|dst_local, 4B/edge.

__global__ void k_binsort(const int* __restrict__ src, const int* __restrict__ dst,
                          int* __restrict__ cursor, uint32_t* __restrict__ ebuf, int E) {
    __shared__ int lhist[NB];
    __shared__ int lbase[NB];
    int chunk = (E + gridDim.x - 1) / gridDim.x;
    int e0 = blockIdx.x * chunk;
    int e1 = min(e0 + chunk, E);
    for (int i = threadIdx.x; i < NB; i += blockDim.x) lhist[i] = 0;
    __syncthreads();
    for (int e = e0 + threadIdx.x; e < e1; e += blockDim.x)
        atomicAdd(&lhist[dst[e] >> 7], 1);
    __syncthreads();
    for (int i = threadIdx.x; i < NB; i += blockDim.x) {
        int c = lhist[i];
        lbase[i] = c ? atomicAdd(&cursor[i], c) : 0;
    }
    __syncthreads();
    for (int i = threadIdx.x; i < NB; i += blockDim.x) lhist[i] = 0;
    __syncthreads();
    for (int e = e0 + threadIdx.x; e < e1; e += blockDim.x) {
        int d = dst[e];
        int b = d >> 7;
        int off = atomicAdd(&lhist[b], 1);
        ebuf[lbase[b] + off] = ((uint32_t)src[e] << 7) | (uint32_t)(d & (NPB - 1));
    }
}

// ---------------- layer 1 GEMM: x(N,512) @ W1(512,8) ----------------

__global__ void k_gemm1(const float* __restrict__ x, const float* __restrict__ W,
                        float* __restrict__ xw, int n) {
    __shared__ float sW[512 * 8];
    for (int i = threadIdx.x; i < 512 * 8; i += blockDim.x) sW[i] = W[i];
    __syncthreads();
    int r = blockIdx.x * blockDim.x + threadIdx.x;
    if (r >= n) return;
    const float4* xr = (const float4*)(x + (size_t)r * 512);
    float acc[8];
#pragma unroll
    for (int c = 0; c < 8; ++c) acc[c] = 0.f;
    for (int t = 0; t < 128; ++t) {
        float4 v = xr[t];
        const float* sw = &sW[t * 32];
#pragma unroll
        for (int c = 0; c < 8; ++c)
            acc[c] += v.x * sw[c] + v.y * sw[8 + c] + v.z * sw[16 + c] + v.w * sw[24 + c];
    }
    float4* xwo = (float4*)(xw + (size_t)r * 8);
    xwo[0] = make_float4(acc[0], acc[1], acc[2], acc[3]);
    xwo[1] = make_float4(acc[4], acc[5], acc[6], acc[7]);
}

// ---------------- small GEMM with fused bias+relu ----------------

template <int FIN, int FOUT, bool RELU>
__global__ void k_gemm_small(const float* __restrict__ h, const float* __restrict__ W,
                             const float* __restrict__ b, float* __restrict__ xw, int n) {
    __shared__ float sW[FIN * FOUT];
    __shared__ float sB[FOUT];
    for (int i = threadIdx.x; i < FIN * FOUT; i += blockDim.x) sW[i] = W[i];
    for (int i = threadIdx.x; i < FOUT; i += blockDim.x) sB[i] = b[i];
    __syncthreads();
    int r = blockIdx.x * blockDim.x + threadIdx.x;
    if (r >= n) return;
    float in[FIN];
    const float4* hp = (const float4*)(h + (size_t)r * FIN);
#pragma unroll
    for (int t = 0; t < FIN / 4; ++t) {
        float4 v = hp[t];
        in[t * 4 + 0] = v.x; in[t * 4 + 1] = v.y; in[t * 4 + 2] = v.z; in[t * 4 + 3] = v.w;
    }
    float4* xwo = (float4*)(xw + (size_t)r * FOUT);
#pragma unroll
    for (int c = 0; c < FOUT; c += 4) {
        float s[4];
#pragma unroll
        for (int j = 0; j < 4; ++j) {
            float a = 0.f;
#pragma unroll
            for (int k = 0; k < FIN; ++k) a += in[k] * sW[k * FOUT + c + j];
            a += sB[c + j];
            if (RELU) a = fmaxf(a, 0.f);
            s[j] = a;
        }
        xwo[c / 4] = make_float4(s[0], s[1], s[2], s[3]);
    }
}

// ---------------- bucket aggregation: one block per bucket, LDS accumulate ----------------
// out[n] = sum_{e:dst=n} xw[src]*norm + xw[n]*dinv[n]^2  (+bias,relu if BR)

template <int F, bool BR>
__global__ void k_agg(const float* __restrict__ xw, const uint32_t* __restrict__ ebuf,
                      const int* __restrict__ row_start, const float* __restrict__ dinv,
                      const float* __restrict__ b, float* __restrict__ out, int n) {
    __shared__ float acc[NPB * F];
    int node0 = blockIdx.x * NPB;
    int nodes = min(NPB, n - node0);
    for (int i = threadIdx.x; i < NPB * F; i += blockDim.x) acc[i] = 0.f;
    __syncthreads();
    int e0 = row_start[node0];
    int e1 = row_start[node0 + nodes];
    const int EPB = 256 / F;
    int c = threadIdx.x & (F - 1);
    int eoff = threadIdx.x / F;
    for (int e = e0 + eoff; e < e1; e += EPB) {
        uint32_t p = ebuf[e];
        int s = (int)(p >> 7);
        int dl = (int)(p & (NPB - 1));
        float norm = dinv[s] * dinv[node0 + dl];
        atomicAdd(&acc[dl * F + c], xw[(size_t)s * F + c] * norm);
    }
    __syncthreads();
    for (int i = threadIdx.x; i < nodes * F; i += blockDim.x) {
        int node = node0 + i / F;
        int cc = i & (F - 1);
        float di = dinv[node];
        float v = acc[i] + xw[(size_t)node * F + cc] * di * di;
        if (BR) v = fmaxf(v + b[cc], 0.f);
        out[(size_t)node * F + cc] = v;
    }
}

// ---------------- head prep: fold W3/b3/Wfc into per-node 16-dot ----------------

__global__ void k_prep_head(const float* __restrict__ W3, const float* __restrict__ b3,
                            const float* __restrict__ Wfc, float* __restrict__ v,
                            float* __restrict__ c) {
    int t = threadIdx.x;
    if (t < 32) {
        int j = t & 15;
        const float* wf = Wfc + (t < 16 ? 0 : 32);
        float a = 0.f;
        for (int k = 0; k < 32; ++k) a += W3[j * 32 + k] * wf[k];
        v[t] = a;
    } else if (t < 34) {
        const float* wf = Wfc + (t == 32 ? 0 : 32);
        float a = 0.f;
        for (int k = 0; k < 32; ++k) a += b3[k] * wf[k];
        c[t - 32] = a;
    }
}

__global__ void k_node_head(const float* __restrict__ S3, const float* __restrict__ v,
                            const float* __restrict__ c, float* __restrict__ pi,
                            float* __restrict__ pj, int n) {
    int r = blockIdx.x * blockDim.x + threadIdx.x;
    if (r >= n) return;
    const float4* sp = (const float4*)(S3 + (size_t)r * 16);
    float a = 0.f, bb = 0.f;
#pragma unroll
    for (int t = 0; t < 4; ++t) {
        float4 s = sp[t];
        a += s.x * v[t * 4 + 0] + s.y * v[t * 4 + 1] + s.z * v[t * 4 + 2] + s.w * v[t * 4 + 3];
        bb += s.x * v[16 + t * 4 + 0] + s.y * v[16 + t * 4 + 1] + s.z * v[16 + t * 4 + 2] + s.w * v[16 + t * 4 + 3];
    }
    pi[r] = a + c[0];
    pj[r] = bb + c[1];
}

__global__ void k_samples_fast(const int2* __restrict__ samples, const float* __restrict__ pi,
                               const float* __restrict__ pj, const float* __restrict__ bfc,
                               float* __restrict__ out, int S) {
    int i = blockIdx.x * blockDim.x + threadIdx.x;
    if (i >= S) return;
    int2 s = samples[i];
    float z = pi[s.x] + pj[s.y] + bfc[0];
    out[i] = 1.0f / (1.0f + __expf(-z));
}

// ---------------- launch ----------------

extern "C" void kernel_launch(void* const* d_in, const int* in_sizes, int n_in,
                              void* d_out, int out_size, void* d_ws, size_t ws_size,
                              hipStream_t stream) {
    const float* x   = (const float*)d_in[0];
    const int*   ei  = (const int*)d_in[1];
    const int*   smp = (const int*)d_in[2];
    const float* W1  = (const float*)d_in[3];
    const float* b1  = (const float*)d_in[4];
    const float* W2  = (const float*)d_in[5];
    const float* b2  = (const float*)d_in[6];
    const float* W3  = (const float*)d_in[7];
    const float* b3  = (const float*)d_in[8];
    const float* Wfc = (const float*)d_in[9];
    const float* bfc = (const float*)d_in[10];
    float* out = (float*)d_out;

    const int E = in_sizes[1] / 2;
    const int S = in_sizes[2] / 2;
    const int N = N_NODES;
    const int* src = ei;
    const int* dst = ei + E;

    char* w = (char*)d_ws;
    size_t off = 0;
    auto alloc = [&](size_t bytes) {
        char* p = w + off;
        off += (bytes + 255) & ~(size_t)255;
        return p;
    };
    int*      cnt       = (int*)alloc(N * 4);
    int*      row_start = (int*)alloc((N + 1) * 4);
    float*    dinv      = (float*)alloc(N * 4);
    int*      cursor    = (int*)alloc(NB * 4);
    uint32_t* ebuf      = (uint32_t*)alloc((size_t)E * 4);
    float*    xw1       = (float*)alloc((size_t)N * 8 * 4);
    float*    h1        = (float*)alloc((size_t)N * 8 * 4);
    float*    S2        = (float*)alloc((size_t)N * 8 * 4);
    float*    h2        = (float*)alloc((size_t)N * 16 * 4);
    float*    S3        = (float*)alloc((size_t)N * 16 * 4);
    float*    vhead     = (float*)alloc(32 * 4);
    float*    chead     = (float*)alloc(2 * 4);
    float*    pi        = (float*)alloc(N * 4);
    float*    pj        = (float*)alloc(N * 4);

    dim3 B(256);

    hipMemsetAsync(cnt, 0, N * 4, stream);
    k_degree<<<dim3((E + 255) / 256), B, 0, stream>>>(dst, cnt, E);
    k_dinv<<<dim3((N + 255) / 256), B, 0, stream>>>(cnt, dinv, N);
    k_scan<<<dim3(1), dim3(1024), 0, stream>>>(cnt, row_start, N);
    k_initcur<<<dim3((NB + 255) / 256), B, 0, stream>>>(row_start, cursor);
    k_binsort<<<dim3(256), B, 0, stream>>>(src, dst, cursor, ebuf, E);

    // layer 1: xw1 = x@W1 ; h1 = relu(agg8(xw1) + b1)
    k_gemm1<<<dim3((N + 255) / 256), B, 0, stream>>>(x, W1, xw1, N);
    k_agg<8, true><<<dim3(NB), B, 0, stream>>>(xw1, ebuf, row_start, dinv, b1, h1, N);

    // layer 2 (linearity): S2 = agg8(h1) ; h2 = relu(S2@W2 + b2)
    k_agg<8, false><<<dim3(NB), B, 0, stream>>>(h1, ebuf, row_start, dinv, nullptr, S2, N);
    k_gemm_small<8, 16, true><<<dim3((N + 255) / 256), B, 0, stream>>>(S2, W2, b2, h2, N);

    // layer 3 (linearity): S3 = agg16(h2) ; W3/b3 folded into head
    k_agg<16, false><<<dim3(NB), B, 0, stream>>>(h2, ebuf, row_start, dinv, nullptr, S3, N);

    // head
    k_prep_head<<<dim3(1), dim3(64), 0, stream>>>(W3, b3, Wfc, vhead, chead);
    k_node_head<<<dim3((N + 255) / 256), B, 0, stream>>>(S3, vhead, chead, pi, pj, N);
    k_samples_fast<<<dim3((S + 255) / 256), B, 0, stream>>>((const int2*)smp, pi, pj, bfc, out, S);
}

// Round 5
// 1263.949 us; speedup vs baseline: 1.1199x; 1.1199x over previous
//
#include <hip/hip_runtime.h>
#include <hip/hip_bf16.h>
#include <cstdint>

#define N_NODES 100000
#define NPB 64                          // nodes per bucket (power of two)
#define NB ((N_NODES + NPB - 1) / NPB)  // 1563 buckets

// ---------------- degree / dinv ----------------

__global__ void k_degree(const int* __restrict__ dst, int* __restrict__ cnt, int E) {
    int e = blockIdx.x * blockDim.x + threadIdx.x;
    if (e < E) atomicAdd(&cnt[dst[e]], 1);
}

__global__ void k_dinv(const int* __restrict__ cnt, float* __restrict__ dinv, int n) {
    int i = blockIdx.x * blockDim.x + threadIdx.x;
    if (i < n) dinv[i] = rsqrtf((float)cnt[i] + 1.0f);
}

// single-block scan: per-bucket edge counts (from per-node cnt) -> bstart[0..NB]
__global__ void k_scan(const int* __restrict__ cnt, int* __restrict__ bstart, int n_nodes) {
    __shared__ int s[1024];
    int t = threadIdx.x;
    const int CPB = (NB + 1023) / 1024;   // buckets per thread
    int b_lo = t * CPB, b_hi = min(b_lo + CPB, NB);
    int sum = 0;
    for (int bb = b_lo; bb < b_hi; ++bb) {
        int lo = bb * NPB, hi = min(lo + NPB, n_nodes);
        for (int i = lo; i < hi; ++i) sum += cnt[i];
    }
    s[t] = sum;
    __syncthreads();
    for (int off = 1; off < 1024; off <<= 1) {
        int v = (t >= off) ? s[t - off] : 0;
        __syncthreads();
        s[t] += v;
        __syncthreads();
    }
    int base = (t == 0) ? 0 : s[t - 1];
    for (int bb = b_lo; bb < b_hi; ++bb) {
        bstart[bb] = base;
        int lo = bb * NPB, hi = min(lo + NPB, n_nodes);
        for (int i = lo; i < hi; ++i) base += cnt[i];
    }
    if (t == 1023) bstart[NB] = base;
}

__global__ void k_initcur(const int* __restrict__ bstart, int* __restrict__ cursor) {
    int b = blockIdx.x * blockDim.x + threadIdx.x;
    if (b < NB) cursor[b] = bstart[b];
}

// ---------------- bucket sort of edges (write-combining friendly) ----------------
// 128 blocks; each histograms its ~25K-edge chunk over NB buckets in LDS,
// reserves one contiguous run per bucket (1 global atomic), scatters packed
// (src<<6)|dst_local (4B/edge) into block-private ~64B runs.

__global__ void k_binsort(const int* __restrict__ src, const int* __restrict__ dst,
                          int* __restrict__ cursor, uint32_t* __restrict__ ebuf, int E) {
    __shared__ int lhist[NB];
    __shared__ int lbase[NB];
    int chunk = (E + gridDim.x - 1) / gridDim.x;
    int e0 = blockIdx.x * chunk;
    int e1 = min(e0 + chunk, E);
    for (int i = threadIdx.x; i < NB; i += blockDim.x) lhist[i] = 0;
    __syncthreads();
    for (int e = e0 + threadIdx.x; e < e1; e += blockDim.x)
        atomicAdd(&lhist[dst[e] >> 6], 1);
    __syncthreads();
    for (int i = threadIdx.x; i < NB; i += blockDim.x) {
        int c = lhist[i];
        lbase[i] = c ? atomicAdd(&cursor[i], c) : 0;
    }
    __syncthreads();
    for (int i = threadIdx.x; i < NB; i += blockDim.x) lhist[i] = 0;
    __syncthreads();
    for (int e = e0 + threadIdx.x; e < e1; e += blockDim.x) {
        int d = dst[e];
        int b = d >> 6;
        int off = atomicAdd(&lhist[b], 1);
        ebuf[lbase[b] + off] = ((uint32_t)src[e] << 6) | (uint32_t)(d & (NPB - 1));
    }
}

// ---------------- layer 1 GEMM: y1 = (x @ W1) * dinv[r] ----------------

__global__ void k_gemm1(const float* __restrict__ x, const float* __restrict__ W,
                        const float* __restrict__ dinv, float* __restrict__ y, int n) {
    __shared__ float sW[512 * 8];
    for (int i = threadIdx.x; i < 512 * 8; i += blockDim.x) sW[i] = W[i];
    __syncthreads();
    int r = blockIdx.x * blockDim.x + threadIdx.x;
    if (r >= n) return;
    const float4* xr = (const float4*)(x + (size_t)r * 512);
    float acc[8];
#pragma unroll
    for (int c = 0; c < 8; ++c) acc[c] = 0.f;
    for (int t = 0; t < 128; ++t) {
        float4 v = xr[t];
        const float* sw = &sW[t * 32];
#pragma unroll
        for (int c = 0; c < 8; ++c)
            acc[c] += v.x * sw[c] + v.y * sw[8 + c] + v.z * sw[16 + c] + v.w * sw[24 + c];
    }
    float di = dinv[r];
    float4* yo = (float4*)(y + (size_t)r * 8);
    yo[0] = make_float4(acc[0] * di, acc[1] * di, acc[2] * di, acc[3] * di);
    yo[1] = make_float4(acc[4] * di, acc[5] * di, acc[6] * di, acc[7] * di);
}

// ---------------- small GEMM, fused bias+relu, output rescaled by dinv ----------------

template <int FIN, int FOUT>
__global__ void k_gemm_small(const float* __restrict__ h, const float* __restrict__ W,
                             const float* __restrict__ b, const float* __restrict__ dinv,
                             float* __restrict__ y, int n) {
    __shared__ float sW[FIN * FOUT];
    __shared__ float sB[FOUT];
    for (int i = threadIdx.x; i < FIN * FOUT; i += blockDim.x) sW[i] = W[i];
    for (int i = threadIdx.x; i < FOUT; i += blockDim.x) sB[i] = b[i];
    __syncthreads();
    int r = blockIdx.x * blockDim.x + threadIdx.x;
    if (r >= n) return;
    float in[FIN];
    const float4* hp = (const float4*)(h + (size_t)r * FIN);
#pragma unroll
    for (int t = 0; t < FIN / 4; ++t) {
        float4 v = hp[t];
        in[t * 4 + 0] = v.x; in[t * 4 + 1] = v.y; in[t * 4 + 2] = v.z; in[t * 4 + 3] = v.w;
    }
    float di = dinv[r];
    float4* yo = (float4*)(y + (size_t)r * FOUT);
#pragma unroll
    for (int c = 0; c < FOUT; c += 4) {
        float s[4];
#pragma unroll
        for (int j = 0; j < 4; ++j) {
            float a = 0.f;
#pragma unroll
            for (int k = 0; k < FIN; ++k) a += in[k] * sW[k * FOUT + c + j];
            s[j] = fmaxf(a + sB[c + j], 0.f) * di;
        }
        yo[c / 4] = make_float4(s[0], s[1], s[2], s[3]);
    }
}

// ---------------- bucket aggregation ----------------
// S[d] = dinv[d] * (sum_{e->d} y[src] + dinv[d]*y[d]);
// if BR: out = relu(S + b)*dinv[d] (producing the next layer's pre-scaled y),
// else:  out = S.
// Per edge: 1 sequential 4B packed read + 1 coalesced row gather + 1 LDS atomic.

template <int F, bool BR>
__global__ void k_agg(const float* __restrict__ y, const uint32_t* __restrict__ ebuf,
                      const int* __restrict__ bstart, const float* __restrict__ dinv,
                      const float* __restrict__ b, float* __restrict__ out, int n) {
    __shared__ float acc[NPB * F];
    int node0 = blockIdx.x * NPB;
    int nodes = min(NPB, n - node0);
    for (int i = threadIdx.x; i < NPB * F; i += blockDim.x) acc[i] = 0.f;
    __syncthreads();
    int e0 = bstart[blockIdx.x];
    int e1 = bstart[blockIdx.x + 1];
    const int EPB = 256 / F;
    int c = threadIdx.x & (F - 1);
    int eoff = threadIdx.x / F;
    int e = e0 + eoff;
    for (; e + 3 * EPB < e1; e += 4 * EPB) {
        uint32_t p0 = ebuf[e];
        uint32_t p1 = ebuf[e + EPB];
        uint32_t p2 = ebuf[e + 2 * EPB];
        uint32_t p3 = ebuf[e + 3 * EPB];
        float v0 = y[(size_t)(p0 >> 6) * F + c];
        float v1 = y[(size_t)(p1 >> 6) * F + c];
        float v2 = y[(size_t)(p2 >> 6) * F + c];
        float v3 = y[(size_t)(p3 >> 6) * F + c];
        atomicAdd(&acc[(p0 & (NPB - 1)) * F + c], v0);
        atomicAdd(&acc[(p1 & (NPB - 1)) * F + c], v1);
        atomicAdd(&acc[(p2 & (NPB - 1)) * F + c], v2);
        atomicAdd(&acc[(p3 & (NPB - 1)) * F + c], v3);
    }
    for (; e < e1; e += EPB) {
        uint32_t p = ebuf[e];
        float v = y[(size_t)(p >> 6) * F + c];
        atomicAdd(&acc[(p & (NPB - 1)) * F + c], v);
    }
    __syncthreads();
    for (int i = threadIdx.x; i < nodes * F; i += blockDim.x) {
        int node = node0 + i / F;
        int cc = i & (F - 1);
        float di = dinv[node];
        float v = di * (acc[i] + di * y[(size_t)node * F + cc]);
        if (BR) v = fmaxf(v + b[cc], 0.f) * di;
        out[(size_t)node * F + cc] = v;
    }
}

// ---------------- head: fold W3/b3/Wfc into per-node scalars ----------------

__global__ void k_prep_head(const float* __restrict__ W3, const float* __restrict__ b3,
                            const float* __restrict__ Wfc, float* __restrict__ v,
                            float* __restrict__ c) {
    int t = threadIdx.x;
    if (t < 32) {
        int j = t & 15;
        const float* wf = Wfc + (t < 16 ? 0 : 32);
        float a = 0.f;
        for (int k = 0; k < 32; ++k) a += W3[j * 32 + k] * wf[k];
        v[t] = a;
    } else if (t < 34) {
        const float* wf = Wfc + (t == 32 ? 0 : 32);
        float a = 0.f;
        for (int k = 0; k < 32; ++k) a += b3[k] * wf[k];
        c[t - 32] = a;
    }
}

__global__ void k_node_head(const float* __restrict__ S3, const float* __restrict__ v,
                            const float* __restrict__ c, float* __restrict__ pi,
                            float* __restrict__ pj, int n) {
    int r = blockIdx.x * blockDim.x + threadIdx.x;
    if (r >= n) return;
    const float4* sp = (const float4*)(S3 + (size_t)r * 16);
    float a = 0.f, bb = 0.f;
#pragma unroll
    for (int t = 0; t < 4; ++t) {
        float4 s = sp[t];
        a += s.x * v[t * 4 + 0] + s.y * v[t * 4 + 1] + s.z * v[t * 4 + 2] + s.w * v[t * 4 + 3];
        bb += s.x * v[16 + t * 4 + 0] + s.y * v[16 + t * 4 + 1] + s.z * v[16 + t * 4 + 2] + s.w * v[16 + t * 4 + 3];
    }
    pi[r] = a + c[0];
    pj[r] = bb + c[1];
}

__global__ void k_samples_fast(const int2* __restrict__ samples, const float* __restrict__ pi,
                               const float* __restrict__ pj, const float* __restrict__ bfc,
                               float* __restrict__ out, int S) {
    int i = blockIdx.x * blockDim.x + threadIdx.x;
    if (i >= S) return;
    int2 s = samples[i];
    float z = pi[s.x] + pj[s.y] + bfc[0];
    out[i] = 1.0f / (1.0f + __expf(-z));
}

// ---------------- launch ----------------

extern "C" void kernel_launch(void* const* d_in, const int* in_sizes, int n_in,
                              void* d_out, int out_size, void* d_ws, size_t ws_size,
                              hipStream_t stream) {
    const float* x   = (const float*)d_in[0];
    const int*   ei  = (const int*)d_in[1];
    const int*   smp = (const int*)d_in[2];
    const float* W1  = (const float*)d_in[3];
    const float* b1  = (const float*)d_in[4];
    const float* W2  = (const float*)d_in[5];
    const float* b2  = (const float*)d_in[6];
    const float* W3  = (const float*)d_in[7];
    const float* b3  = (const float*)d_in[8];
    const float* Wfc = (const float*)d_in[9];
    const float* bfc = (const float*)d_in[10];
    float* out = (float*)d_out;

    const int E = in_sizes[1] / 2;
    const int S = in_sizes[2] / 2;
    const int N = N_NODES;
    const int* src = ei;
    const int* dst = ei + E;

    char* w = (char*)d_ws;
    size_t off = 0;
    auto alloc = [&](size_t bytes) {
        char* p = w + off;
        off += (bytes + 255) & ~(size_t)255;
        return p;
    };
    int*      cnt    = (int*)alloc(N * 4);
    int*      bstart = (int*)alloc((NB + 1) * 4);
    int*      cursor = (int*)alloc(NB * 4);
    float*    dinv   = (float*)alloc(N * 4);
    uint32_t* ebuf   = (uint32_t*)alloc((size_t)E * 4);
    float*    y1     = (float*)alloc((size_t)N * 8 * 4);
    float*    y2     = (float*)alloc((size_t)N * 8 * 4);
    float*    S2     = (float*)alloc((size_t)N * 8 * 4);
    float*    y3     = (float*)alloc((size_t)N * 16 * 4);
    float*    S3     = (float*)alloc((size_t)N * 16 * 4);
    float*    vhead  = (float*)alloc(32 * 4);
    float*    chead  = (float*)alloc(2 * 4);
    float*    pi     = (float*)alloc(N * 4);
    float*    pj     = (float*)alloc(N * 4);

    dim3 B(256);

    hipMemsetAsync(cnt, 0, N * 4, stream);
    k_degree<<<dim3((E + 255) / 256), B, 0, stream>>>(dst, cnt, E);
    k_dinv<<<dim3((N + 255) / 256), B, 0, stream>>>(cnt, dinv, N);
    k_scan<<<dim3(1), dim3(1024), 0, stream>>>(cnt, bstart, N);
    k_initcur<<<dim3((NB + 255) / 256), B, 0, stream>>>(bstart, cursor);
    k_binsort<<<dim3(128), B, 0, stream>>>(src, dst, cursor, ebuf, E);

    // layer 1: y1 = (x@W1)*dinv ; y2 = relu(dinv*(agg y1) + b1)*dinv
    k_gemm1<<<dim3((N + 255) / 256), B, 0, stream>>>(x, W1, dinv, y1, N);
    k_agg<8, true><<<dim3(NB), B, 0, stream>>>(y1, ebuf, bstart, dinv, b1, y2, N);

    // layer 2: S2 = dinv*(agg y2) ; y3 = relu(S2@W2+b2)*dinv
    k_agg<8, false><<<dim3(NB), B, 0, stream>>>(y2, ebuf, bstart, dinv, nullptr, S2, N);
    k_gemm_small<8, 16><<<dim3((N + 255) / 256), B, 0, stream>>>(S2, W2, b2, dinv, y3, N);

    // layer 3: S3 = dinv*(agg y3) ; W3/b3 folded into head
    k_agg<16, false><<<dim3(NB), B, 0, stream>>>(y3, ebuf, bstart, dinv, nullptr, S3, N);

    // head
    k_prep_head<<<dim3(1), dim3(64), 0, stream>>>(W3, b3, Wfc, vhead, chead);
    k_node_head<<<dim3((N + 255) / 256), B, 0, stream>>>(S3, vhead, chead, pi, pj, N);
    k_samples_fast<<<dim3((S + 255) / 256), B, 0, stream>>>((const int2*)smp, pi, pj, bfc, out, S);
}